// Round 3
// baseline (105.350 us; speedup 1.0000x reference)
//
#include <hip/hip_runtime.h>

// Gaussian RBF soft-histogram:
//   out[b,o,p] = sum_j exp( -(x[b,j,p] - c[o,j])^2 / (2*w[o,j]^2) )
// x: [B=8, CIN=8, HW=65536] f32; c,w: [COUT=16, CIN=8]; out: [B=8, COUT=16, HW] f32
//
// R3: minimum-issue version. Evidence so far: dur_us (82-84us) is dominated by
// harness poison/restore memops (our kernel never appears in top-5 dispatches,
// all of which are 44us fills -> kernel < 44us). R1 (2 waves/SIMD) == R2
// (8 waves/SIMD) killed the latency theory; this round minimizes issue count:
//  - constants (-c, -log2e/(2w^2)) precomputed once by a 128-thread pre-kernel
//    into d_ws; main kernel reads them as wave-uniform s_loads (no LDS, no
//    syncthreads, no per-thread rcp, zero VALU issue for constants)
//  - 2 pixels/thread via float2 -> packed v_pk_* f32 ops halve VALU issue,
//    dwordx2 loads/stores halve mem-issue per pixel; 4096 waves = 4/SIMD
//  - direct (x-c)^2 form kept (no polynomial expansion) for numerical safety
//    against tiny bin_widths (cancellation would blow the 0.1575 threshold)

constexpr int CIN   = 8;
constexpr int COUT  = 16;
constexpr int HW    = 256 * 256;   // 65536
constexpr int HW2   = HW / 2;      // float2 elements per plane
constexpr int BATCH = 8;

__global__ __launch_bounds__(128) void rbf_precompute_kernel(
    const float* __restrict__ centers,
    const float* __restrict__ widths,
    float2* __restrict__ cw)
{
    const int i = threadIdx.x;     // 128 = COUT*CIN
    const float w = widths[i];
    const float negk = -1.4426950408889634f / (2.0f * w * w);
    cw[i] = make_float2(-centers[i], negk);
}

__global__ __launch_bounds__(256, 8) void rbf_hist_kernel(
    const float* __restrict__ x,
    const float2* __restrict__ cw,   // (-c, negk) in d_ws, 128 entries
    float* __restrict__ out)
{
    const int t  = blockIdx.x * 256 + threadIdx.x;  // 0 .. B*HW2-1
    const int b  = t >> 15;                         // t / HW2
    const int p2 = t & (HW2 - 1);                   // t % HW2

    const float2* __restrict__ xv = (const float2*)x;
    float2* __restrict__ ov = (float2*)out;

    // Load this thread's 8 input channels (x read exactly once from HBM)
    float2 xr[CIN];
#pragma unroll
    for (int j = 0; j < CIN; ++j) {
        xr[j] = xv[(b * CIN + j) * HW2 + p2];
    }

#pragma unroll 2
    for (int o = 0; o < COUT; ++o) {
        float2 acc = make_float2(0.f, 0.f);
#pragma unroll
        for (int j = 0; j < CIN; ++j) {
            const float2 k = cw[o * CIN + j];   // wave-uniform -> s_load, K$-hot
            const float d0 = xr[j].x + k.x;     // x - c  (k.x = -c)
            const float d1 = xr[j].y + k.x;
            acc.x += __builtin_amdgcn_exp2f((k.y * d0) * d0);
            acc.y += __builtin_amdgcn_exp2f((k.y * d1) * d1);
        }
        ov[(b * COUT + o) * HW2 + p2] = acc;
    }
}

extern "C" void kernel_launch(void* const* d_in, const int* in_sizes, int n_in,
                              void* d_out, int out_size, void* d_ws, size_t ws_size,
                              hipStream_t stream) {
    const float* x       = (const float*)d_in[0];
    const float* centers = (const float*)d_in[1];
    const float* widths  = (const float*)d_in[2];
    float* out           = (float*)d_out;
    float2* cw           = (float2*)d_ws;          // 128 float2 = 1 KiB scratch

    rbf_precompute_kernel<<<1, 128, 0, stream>>>(centers, widths, cw);

    const int total_threads = BATCH * HW2;         // 262144 threads, 2 px each
    const int block = 256;
    const int grid  = total_threads / block;       // 1024 blocks

    rbf_hist_kernel<<<grid, block, 0, stream>>>(x, cw, out);
}

// Round 4
// 83.901 us; speedup vs baseline: 1.2556x; 1.2556x over previous
//
#include <hip/hip_runtime.h>

// Gaussian RBF soft-histogram:
//   out[b,o,p] = sum_j exp( -(x[b,j,p] - c[o,j])^2 / (2*w[o,j]^2) )
// x: [B=8, CIN=8, HW=65536] f32; c,w: [COUT=16, CIN=8]; out: [B=8, COUT=16, HW] f32
//
// R4: revert R3's extra-launch regression (+23us: graph-node overhead +
// s_load lgkm stalls). Single launch, R1's float4 structure (minimal mem +
// address issue; x read exactly once via dwordx4), constants staged to LDS
// in-kernel as (-c, -log2e/(2w^2)) — broadcast ds_reads, conflict-free.
// Direct (x-c)^2 form (no polynomial expansion): bin_widths ~ N(0,1) can be
// ~0.01 -> k ~ 5e3; expanded-form cancellation would inject ~1% exponent
// error and risk the 0.1575 absmax threshold.
//
// Evidence ledger: R1 (float4, 2 waves/SIMD) 83.7us == R2 (scalar, 8
// waves/SIMD) 82.3us despite ~3x issue-count and 4x occupancy differences;
// kernel never appears in top-5 dispatches (all harness 268MB poison fills
// @44us) -> dur_us = fixed harness overhead (~70us) + kernel (~8-12us,
// near the 48MiB/6.3TBps = 7.6us HBM floor + 67.1M v_exp_f32 issue).

constexpr int CIN   = 8;
constexpr int COUT  = 16;
constexpr int HW    = 256 * 256;   // 65536
constexpr int HW4   = HW / 4;      // float4 elements per plane
constexpr int BATCH = 8;

__global__ __launch_bounds__(256) void rbf_hist_kernel(
    const float* __restrict__ x,
    const float* __restrict__ centers,
    const float* __restrict__ widths,
    float* __restrict__ out)
{
    __shared__ float2 s_cn[COUT * CIN];   // (-c, negk), negk = -log2e/(2 w^2)

    const int tid = threadIdx.x;
    if (tid < COUT * CIN) {
        const float w = widths[tid];
        const float negk = -1.4426950408889634f / (2.0f * w * w);
        s_cn[tid] = make_float2(-centers[tid], negk);
    }
    __syncthreads();

    const int t  = blockIdx.x * 256 + tid;   // 0 .. B*HW4-1 (131071)
    const int b  = t >> 14;                  // t / HW4
    const int s4 = t & (HW4 - 1);            // t % HW4

    const float4* __restrict__ xv = (const float4*)x;
    float4* __restrict__ ov = (float4*)out;

    // Load this thread's 8 input channels (x read exactly once from HBM)
    float4 xr[CIN];
#pragma unroll
    for (int j = 0; j < CIN; ++j) {
        xr[j] = xv[(b * CIN + j) * HW4 + s4];
    }

#pragma unroll 4
    for (int o = 0; o < COUT; ++o) {
        float4 acc = make_float4(0.f, 0.f, 0.f, 0.f);
#pragma unroll
        for (int j = 0; j < CIN; ++j) {
            const float2 cn = s_cn[o * CIN + j];
            const float nc = cn.x;   // -c
            const float nk = cn.y;   // -log2e/(2w^2)
            const float d0 = xr[j].x + nc;
            const float d1 = xr[j].y + nc;
            const float d2 = xr[j].z + nc;
            const float d3 = xr[j].w + nc;
            acc.x += __builtin_amdgcn_exp2f((nk * d0) * d0);
            acc.y += __builtin_amdgcn_exp2f((nk * d1) * d1);
            acc.z += __builtin_amdgcn_exp2f((nk * d2) * d2);
            acc.w += __builtin_amdgcn_exp2f((nk * d3) * d3);
        }
        ov[(b * COUT + o) * HW4 + s4] = acc;
    }
}

extern "C" void kernel_launch(void* const* d_in, const int* in_sizes, int n_in,
                              void* d_out, int out_size, void* d_ws, size_t ws_size,
                              hipStream_t stream) {
    const float* x       = (const float*)d_in[0];
    const float* centers = (const float*)d_in[1];
    const float* widths  = (const float*)d_in[2];
    float* out           = (float*)d_out;

    const int total_threads = BATCH * HW4;     // 131072 threads, 4 px each
    const int block = 256;
    const int grid  = total_threads / block;   // 512 blocks

    rbf_hist_kernel<<<grid, block, 0, stream>>>(x, centers, widths, out);
}